// Round 1
// 650.596 us; speedup vs baseline: 1.3508x; 1.3508x over previous
//
#include <hip/hip_runtime.h>
#include <hip/hip_bf16.h>

// ---------------------------------------------------------------------------
// KV-cached MHA, MI355X. Round 1 changes vs baseline:
//  * bf16 pre-conversion pass for q/k/v + Wq/Wk/Wv/Wo; copy_cache also emits
//    bf16 cache mirrors -> all GEMMs move to the m97 structure
//    (global_load_lds width=16, linear LDS, 2-barrier loop, XCD swizzle).
//  * attn_k: balanced qb<->15-qb block remap (kills the 16x CU imbalance),
//    Kt XOR swizzle (16-way -> free), Vt key-pair-packed b32 stores with
//    chunk swizzle (16-way scalar -> 4-way b32), Pw chunk swizzle
//    (8-way -> 4-way), staging reads from bf16 cache mirrors.
// ---------------------------------------------------------------------------

typedef __bf16 bf16x8 __attribute__((ext_vector_type(8)));
typedef __bf16 bf16x4 __attribute__((ext_vector_type(4)));
typedef unsigned short u16x8 __attribute__((ext_vector_type(8)));
typedef float  f32x4  __attribute__((ext_vector_type(4)));
typedef unsigned int u32;

#define MFMA16(a, b, c) __builtin_amdgcn_mfma_f32_16x16x32_bf16((a), (b), (c), 0, 0, 0)

// async global->LDS, 16B per lane. LDS base must be wave-uniform; HW writes
// lane l's data at base + l*16.
__device__ __forceinline__ void async16(__bf16* lds, const __bf16* g) {
    __builtin_amdgcn_global_load_lds(
        (__attribute__((address_space(1))) void*)g,
        (__attribute__((address_space(3))) void*)lds, 16, 0, 0);
}

// ---------------------------------------------------------------------------
// fp32 -> bf16 conversion: query/key/value (2^20 8-elem units each) and
// Wq/Wk/Wv/Wo (2^19 units each). Pure BW pass, ~251 MB traffic.
// ---------------------------------------------------------------------------
__global__ __launch_bounds__(256) void cvt_all(
    const float* __restrict__ q, const float* __restrict__ k, const float* __restrict__ v,
    const float* __restrict__ wq, const float* __restrict__ wk,
    const float* __restrict__ wv, const float* __restrict__ wo,
    __bf16* __restrict__ dq, __bf16* __restrict__ dk, __bf16* __restrict__ dv,
    __bf16* __restrict__ dwq, __bf16* __restrict__ dwk,
    __bf16* __restrict__ dwv, __bf16* __restrict__ dwo) {
    const int nthreads = gridDim.x * blockDim.x;
    for (int i = blockIdx.x * blockDim.x + threadIdx.x; i < 5242880; i += nthreads) {
        const float* s;
        __bf16* d;
        int off;
        if (i < (3 << 20)) {
            const int r = i >> 20;
            off = i & ((1 << 20) - 1);
            s = (r == 0) ? q : (r == 1) ? k : v;
            d = (r == 0) ? dq : (r == 1) ? dk : dv;
        } else {
            const int j = i - (3 << 20);
            const int r = j >> 19;
            off = j & ((1 << 19) - 1);
            s = (r == 0) ? wq : (r == 1) ? wk : (r == 2) ? wv : wo;
            d = (r == 0) ? dwq : (r == 1) ? dwk : (r == 2) ? dwv : dwo;
        }
        const f32x4 x0 = *(const f32x4*)(s + (size_t)off * 8);
        const f32x4 x1 = *(const f32x4*)(s + (size_t)off * 8 + 4);
        bf16x8 o;
#pragma unroll
        for (int j = 0; j < 4; j++) {
            o[j]     = (__bf16)x0[j];
            o[j + 4] = (__bf16)x1[j];
        }
        *(bf16x8*)(d + (size_t)off * 8) = o;
    }
}

// ---------------------------------------------------------------------------
// GEMM: C[M=4096, N=2048] = A[4096,2048]bf16 @ W[2048,2048]bf16^T + bias(f32)
// m97 structure: 128x128 tile, BK=32, 4 waves, global_load_lds dwordx4,
// linear LDS (T2 swizzle measured null on 128^2+2-phase), 2 barriers/K-step.
// MODE 0: C fp32 row-major [4096][2048]
// MODE 1: C bf16 scattered to ws_q [B][H][1024][128]
// MODE 2: C fp32 scattered to new_k/new_v [B][H][2048][128], t offset +1024
// ---------------------------------------------------------------------------
template <int MODE>
__global__ __launch_bounds__(256) void gemm_bf(const __bf16* __restrict__ A,
                                               const __bf16* __restrict__ W,
                                               const float* __restrict__ bias,
                                               void* __restrict__ Cv) {
    constexpr int K = 2048;
    __shared__ __bf16 aT[128 * 32];   // [row][k] row-major, linear (gload_lds dest)
    __shared__ __bf16 bT[128 * 32];

    float* Cf = (float*)Cv;
    __bf16* Cb = (__bf16*)Cv;

    const int tid = threadIdx.x;
    const int w = tid >> 6;
    const int lane = tid & 63;

    // XCD swizzle: 512 blocks, 512%8==0 -> simple remap is bijective.
    // Consecutive dispatch (same XCD) gets contiguous m-panels -> A reuse in L2.
    const int lin = (blockIdx.y << 4) | blockIdx.x;
    const int swz = ((lin & 7) << 6) | (lin >> 3);
    const int m0 = (swz >> 4) << 7;
    const int n0 = (swz & 15) << 7;

    const int wr = w >> 1, wc = w & 1;
    const int g = lane >> 4, c = lane & 15;

    // staging: wave w owns rows [w*32, w*32+32); two 1KB wave-loads per tile.
    // lane l -> row w*32 + (l>>2), k-chunk (l&3)*8; LDS linear = base + l*16.
    const int srow = w * 32 + (lane >> 2);
    const int kch = (lane & 3) * 8;
    const __bf16* gA0 = A + (size_t)(m0 + srow) * K + kch;
    const __bf16* gB0 = W + (size_t)(n0 + srow) * K + kch;
    __bf16* lA0 = &aT[w * 1024];
    __bf16* lB0 = &bT[w * 1024];

    f32x4 acc[4][4] = {};
    const int arow = wr * 64 + c;
    const int brow = wc * 64 + c;
    const int koff = g * 8;

    for (int k0 = 0; k0 < K; k0 += 32) {
        async16(lA0,       gA0 + k0);
        async16(lA0 + 512, gA0 + 16 * K + k0);
        async16(lB0,       gB0 + k0);
        async16(lB0 + 512, gB0 + 16 * K + k0);
        __syncthreads();   // drains vmcnt -> staged tile visible; also protects
                           // prior iteration (2nd barrier below orders reads)
        bf16x8 af[4], bfr[4];
#pragma unroll
        for (int t = 0; t < 4; t++) {
            af[t]  = *(const bf16x8*)&aT[(arow + t * 16) * 32 + koff];
            bfr[t] = *(const bf16x8*)&bT[(brow + t * 16) * 32 + koff];
        }
#pragma unroll
        for (int ti = 0; ti < 4; ti++)
#pragma unroll
            for (int tj = 0; tj < 4; tj++)
                acc[ti][tj] = MFMA16(af[ti], bfr[tj], acc[ti][tj]);
        __syncthreads();   // all waves' LDS reads done before next overwrite
    }

    // epilogue: C/D layout col = lane&15 (n), row = (lane>>4)*4 + reg (m)
#pragma unroll
    for (int tj = 0; tj < 4; tj++) {
        const int gcol = n0 + wc * 64 + tj * 16 + c;
        const float bv = bias[gcol];
#pragma unroll
        for (int ti = 0; ti < 4; ti++) {
            const int growb = m0 + wr * 64 + ti * 16 + g * 4;
#pragma unroll
            for (int r = 0; r < 4; r++) {
                const float v = acc[ti][tj][r] + bv;
                const int row = growb + r;
                if (MODE == 0) {
                    Cf[(size_t)row * 2048 + gcol] = v;
                } else {
                    const int b = row >> 10, t = row & 1023;
                    const int h = gcol >> 7, dh = gcol & 127;
                    if (MODE == 1)
                        Cb[(((size_t)(b * 16 + h) * 1024) + t) * 128 + dh] = (__bf16)v;
                    else
                        Cf[(((size_t)(b * 16 + h) * 2048) + 1024 + t) * 128 + dh] = v;
                }
            }
        }
    }
}

// ---------------------------------------------------------------------------
// Copy cache_key/cache_value [B][1024][2048] fp32 -> new_k/new_v
// [B][H][2048][128] fp32 (cache half) AND emit bf16 mirrors in source layout
// for the attention kernel.
// ---------------------------------------------------------------------------
__global__ __launch_bounds__(256) void copy_cache(const float* __restrict__ ck,
                                                  const float* __restrict__ cv,
                                                  float* __restrict__ nk,
                                                  float* __restrict__ nv,
                                                  __bf16* __restrict__ ckb,
                                                  __bf16* __restrict__ cvb) {
    const int nthreads = gridDim.x * blockDim.x;
    for (int i = blockIdx.x * blockDim.x + threadIdx.x; i < 4194304; i += nthreads) {
        const int sel = i >> 21;         // 0 = key, 1 = value
        const int j = i & 2097151;       // output chunk index (4 floats)
        const int dh4 = j & 31;
        const int t = (j >> 5) & 1023;
        const int h = (j >> 15) & 15;
        const int b = j >> 19;
        const float* src = sel ? cv : ck;
        float* dst = sel ? nv : nk;
        __bf16* dstb = sel ? cvb : ckb;
        const size_t si = ((size_t)(b << 10) + t) * 2048 + (h << 7) + (dh4 << 2);
        const size_t di = ((size_t)b << 22) + ((size_t)h << 18) + (t << 7) + (dh4 << 2);
        const f32x4 x = *(const f32x4*)&src[si];
        *(f32x4*)&dst[di] = x;
        bf16x4 bx;
#pragma unroll
        for (int e = 0; e < 4; e++) bx[e] = (__bf16)x[e];
        *(bf16x4*)&dstb[si] = bx;
    }
}

// ---------------------------------------------------------------------------
// Flash attention over the cache, causal (key <= qrow).
// Block = 64 q-rows (4 waves x 16 rows), K-tile = 32 keys.
// Balanced block remap: qb paired with 15-qb at stride 256 in dispatch order
// so every CU's 4 blocks sum to the same trip count (68).
// Kt: [key][128] bf16 with 16B-chunk XOR swizzle (chunk ^= key&7) ->
//     ds_read_b128 conflict-free (was 16-way).
// Vt: u32[dh][16] holding key-pairs; write = 8x b32 (4-way), read = b128
//     conflict-free via chunk ^= (dh>>3)&3.
// Pw: chunk ^= prow>>2 -> 4-way writes (was 8-way), conflict-free reads.
// ---------------------------------------------------------------------------
__global__ __launch_bounds__(256) void attn_k(const __bf16* __restrict__ Qw,
                                              const __bf16* __restrict__ cK,
                                              const __bf16* __restrict__ cV,
                                              __bf16* __restrict__ O) {
    __shared__ __bf16 Kt[32 * 128];
    __shared__ u32 Vt32[128 * 16];
    __shared__ __bf16 Pw[4][16 * 32];

    const int tid = threadIdx.x;
    const int w = tid >> 6;
    const int lane = tid & 63;
    const int g = lane >> 4, c = lane & 15;

    // balanced remap over 1024 blocks: chunk k (0..3), idx (0..255);
    // odd chunks mirror qb so lin and lin+256 sum to constant work.
    const int lin = blockIdx.x + (blockIdx.y << 4) + (blockIdx.z << 8);
    const int chunk = lin >> 8, idx = lin & 255;
    int qb = idx & 15;
    if (chunk & 1) qb = 15 - qb;
    const int bh = (idx >> 4) + (chunk << 4);
    const int b = bh >> 4, h = bh & 15;
    const int q0 = qb << 6;
    const float inv_scale = 0.08838834764831845f; // 1/sqrt(128)

    // Q A-fragments (A[m=lane&15][k=(lane>>4)*8+j]), held for the whole block
    const __bf16* qbase = Qw + (((size_t)(b * 16 + h) * 1024) + q0 + w * 16) * 128;
    bf16x8 qf[4];
#pragma unroll
    for (int dc = 0; dc < 4; dc++)
        qf[dc] = *(const bf16x8*)&qbase[c * 128 + dc * 32 + g * 8];

    f32x4 accO[8] = {};
    float m_run[4], l_run[4];
#pragma unroll
    for (int r = 0; r < 4; r++) { m_run[r] = -1e30f; l_run[r] = 0.0f; }

    const int trips = (q0 >> 5) + 2; // covers keys 0 .. q0+63
    const __bf16* kb = cK + (size_t)b * 1024 * 2048 + h * 128;
    const __bf16* vb = cV + (size_t)b * 1024 * 2048 + h * 128;

    // K staging: thread owns key skey, 16 dh at sdh (2x bf16x8 loads)
    const int skey = tid >> 3, sdh = (tid & 7) * 16;
    // V staging: thread owns key pair {2kp, 2kp+1}, 8 dh at db*8
    const int kp = tid >> 4, db = tid & 15;
    const int vcol = (((kp >> 2) ^ (db & 3)) << 2) | (kp & 3);

    for (int kt = 0; kt < trips; kt++) {
        const int k0 = kt * 32;
        const bf16x8 k_lo = *(const bf16x8*)&kb[(size_t)(k0 + skey) * 2048 + sdh];
        const bf16x8 k_hi = *(const bf16x8*)&kb[(size_t)(k0 + skey) * 2048 + sdh + 8];
        const bf16x8 v0 = *(const bf16x8*)&vb[(size_t)(k0 + 2 * kp) * 2048 + db * 8];
        const bf16x8 v1 = *(const bf16x8*)&vb[(size_t)(k0 + 2 * kp + 1) * 2048 + db * 8];
        __syncthreads();   // prior iteration's Kt/Vt reads complete
        {
            const int ss = skey & 7, ch0 = (tid & 7) * 2;
            *(bf16x8*)&Kt[skey * 128 + ((ch0 ^ ss) << 3)]       = k_lo;
            *(bf16x8*)&Kt[skey * 128 + (((ch0 + 1) ^ ss) << 3)] = k_hi;
        }
        {
            const u16x8 pa = __builtin_bit_cast(u16x8, v0);
            const u16x8 pb = __builtin_bit_cast(u16x8, v1);
#pragma unroll
            for (int j = 0; j < 8; j++)
                Vt32[(db * 8 + j) * 16 + vcol] = (u32)pa[j] | ((u32)pb[j] << 16);
        }
        __syncthreads();   // staging visible

        // S = Q @ K^T  (two 16-col tiles over this 32-key tile)
        f32x4 s_acc[2] = {};
#pragma unroll
        for (int nt = 0; nt < 2; nt++) {
            const int krow = nt * 16 + c;
            const int ks = krow & 7;
#pragma unroll
            for (int dc = 0; dc < 4; dc++) {
                const bf16x8 kf =
                    *(const bf16x8*)&Kt[krow * 128 + (((dc * 4 + g) ^ ks) << 3)];
                s_acc[nt] = MFMA16(qf[dc], kf, s_acc[nt]);
            }
        }

        // mask + online softmax (this lane holds rows g*4+r, cols c / c+16)
        float p[2][4], alpha[4];
#pragma unroll
        for (int r = 0; r < 4; r++) {
            const int qrow = q0 + w * 16 + g * 4 + r;
            float s0 = (k0 + c      <= qrow) ? s_acc[0][r] * inv_scale : -1e30f;
            float s1 = (k0 + 16 + c <= qrow) ? s_acc[1][r] * inv_scale : -1e30f;
            float rm = fmaxf(s0, s1);
            rm = fmaxf(rm, __shfl_xor(rm, 1));
            rm = fmaxf(rm, __shfl_xor(rm, 2));
            rm = fmaxf(rm, __shfl_xor(rm, 4));
            rm = fmaxf(rm, __shfl_xor(rm, 8));
            const float mnew = fmaxf(m_run[r], rm);
            alpha[r] = __expf(m_run[r] - mnew);
            const float p0 = __expf(s0 - mnew);
            const float p1 = __expf(s1 - mnew);
            p[0][r] = p0; p[1][r] = p1;
            float ps = p0 + p1;
            ps += __shfl_xor(ps, 1);
            ps += __shfl_xor(ps, 2);
            ps += __shfl_xor(ps, 4);
            ps += __shfl_xor(ps, 8);
            l_run[r] = alpha[r] * l_run[r] + ps;
            m_run[r] = mnew;
        }
#pragma unroll
        for (int nt2 = 0; nt2 < 8; nt2++)
#pragma unroll
            for (int r = 0; r < 4; r++)
                accO[nt2][r] *= alpha[r];

        // P -> LDS (swizzled [qrow][key] write), re-read as A-fragment
#pragma unroll
        for (int nt = 0; nt < 2; nt++)
#pragma unroll
            for (int r = 0; r < 4; r++)
                Pw[w][(g * 4 + r) * 32 + ((((nt << 1) | (c >> 3)) ^ g) << 3) + (c & 7)] =
                    (__bf16)p[nt][r];
        __syncthreads();

        const bf16x8 pf = *(const bf16x8*)&Pw[w][c * 32 + ((g ^ ((c >> 2) & 3)) << 3)];
#pragma unroll
        for (int nt2 = 0; nt2 < 8; nt2++) {
            const int vrow = nt2 * 16 + c;
            const bf16x8 vf = *(const bf16x8*)&(
                (const __bf16*)Vt32)[vrow * 32 + ((g ^ ((vrow >> 3) & 3)) << 3)];
            accO[nt2] = MFMA16(pf, vf, accO[nt2]);
        }
    }

    // epilogue: normalize and store bf16 to ws_attn [4096][2048]
#pragma unroll
    for (int nt2 = 0; nt2 < 8; nt2++)
#pragma unroll
        for (int r = 0; r < 4; r++) {
            const float v = accO[nt2][r] / l_run[r];
            const int row = b * 1024 + q0 + w * 16 + g * 4 + r;
            const int col = h * 128 + nt2 * 16 + c;
            O[(size_t)row * 2048 + col] = (__bf16)v;
        }
}

// ---------------------------------------------------------------------------
extern "C" void kernel_launch(void* const* d_in, const int* in_sizes, int n_in,
                              void* d_out, int out_size, void* d_ws, size_t ws_size,
                              hipStream_t stream) {
    const float* query       = (const float*)d_in[0];
    const float* key         = (const float*)d_in[1];
    const float* value       = (const float*)d_in[2];
    const float* cache_key   = (const float*)d_in[3];
    const float* cache_value = (const float*)d_in[4];
    const float* Wq = (const float*)d_in[5];
    const float* bq = (const float*)d_in[6];
    const float* Wk = (const float*)d_in[7];
    const float* bk = (const float*)d_in[8];
    const float* Wv = (const float*)d_in[9];
    const float* bv = (const float*)d_in[10];
    const float* Wo = (const float*)d_in[11];
    const float* bo = (const float*)d_in[12];

    float* out   = (float*)d_out;              // [4096][2048] fp32
    float* new_k = out + 8388608;              // [B][H][2048][128] fp32
    float* new_v = out + 25165824;

    // workspace layout (bf16 elems), total ~151 MB
    __bf16* p = (__bf16*)d_ws;
    __bf16* ws_q    = p; p += 8388608;         // [B][H][1024][128]
    __bf16* ws_attn = p; p += 8388608;         // [4096][2048]
    __bf16* q_bf    = p; p += 8388608;         // [4096][2048]
    __bf16* k_bf    = p; p += 8388608;
    __bf16* v_bf    = p; p += 8388608;
    __bf16* wq_bf   = p; p += 4194304;         // [2048][2048]
    __bf16* wk_bf   = p; p += 4194304;
    __bf16* wv_bf   = p; p += 4194304;
    __bf16* wo_bf   = p; p += 4194304;
    __bf16* ck_bf   = p; p += 8388608;         // [B][1024][2048]
    __bf16* cv_bf   = p;

    const dim3 gemm_grid(16, 32);              // N/128 x M/128

    copy_cache<<<4096, 256, 0, stream>>>(cache_key, cache_value, new_k, new_v,
                                         ck_bf, cv_bf);
    cvt_all<<<2048, 256, 0, stream>>>(query, key, value, Wq, Wk, Wv, Wo,
                                      q_bf, k_bf, v_bf, wq_bf, wk_bf, wv_bf, wo_bf);
    gemm_bf<1><<<gemm_grid, 256, 0, stream>>>(q_bf, wq_bf, bq, ws_q);
    gemm_bf<2><<<gemm_grid, 256, 0, stream>>>(k_bf, wk_bf, bk, new_k);
    gemm_bf<2><<<gemm_grid, 256, 0, stream>>>(v_bf, wv_bf, bv, new_v);
    attn_k<<<dim3(16, 16, 4), 256, 0, stream>>>(ws_q, ck_bf, cv_bf, ws_attn);
    gemm_bf<0><<<gemm_grid, 256, 0, stream>>>(ws_attn, wo_bf, bo, out);
}